// Round 5
// baseline (124.856 us; speedup 1.0000x reference)
//
#include <hip/hip_runtime.h>

#define NDIMS 3
#define H_HALF 256
#define F_DIM 16
#define PI_F 3.14159265358979323846f

typedef _Float16 half8_t __attribute__((ext_vector_type(8)));
typedef __fp16 pk2_t __attribute__((ext_vector_type(2)));   // return type of cvt_pkrtz
typedef float float4_t __attribute__((ext_vector_type(4)));

#if __has_builtin(__builtin_amdgcn_fractf)
#define FRACT1(u) __builtin_amdgcn_fractf(u)
#else
#define FRACT1(u) ((u) - floorf(u))
#endif
// v_sin_f32/v_cos_f32 take REVOLUTIONS (sin(2*pi*u)); input pre-reduced to [0,1).
#if __has_builtin(__builtin_amdgcn_sinf)
#define SIN2PI(u) __builtin_amdgcn_sinf(u)
#define COS2PI(u) __builtin_amdgcn_cosf(u)
#else
#define SIN2PI(u) __sinf(6.283185307f * (u))
#define COS2PI(u) __cosf(6.283185307f * (u))
#endif

// pack two f32 into an f16x2 dword (v_cvt_pkrtz_f16_f32)
static __device__ __forceinline__ unsigned int pk(float lo, float hi) {
    const pk2_t p = __builtin_amdgcn_cvt_pkrtz(lo, hi);
    return __builtin_bit_cast(unsigned int, p);
}

// ---------------------------------------------------------------------------
// cond: c[n,f] = 1 / trapz(relu(y(t)), t), t = linspace(0.01, 1, 100).
// One block per (n,f); 128 threads, thread = t-sample; block-uniform factor
// addresses -> s_load broadcast; 256-step angle-addition recurrence (proven R2).
// ---------------------------------------------------------------------------
__global__ __launch_bounds__(128) void cond_kernel(const float* __restrict__ fr,
                                                   const float* __restrict__ fi,
                                                   float* __restrict__ c_out) {
    const int n = blockIdx.x >> 4;
    const int f = blockIdx.x & 15;
    const int tid = threadIdx.x;
    float contrib = 0.f;
    if (tid < 100) {
        const float t = 0.01f + 0.01f * (float)tid;
        const float beta = 2.f * PI_F * t;
        const float cb = __cosf(beta), sb = __sinf(beta);
        float cj = cb, sj = sb;   // cos/sin(2pi*1*t)
        float acc = 0.f;
        #pragma unroll 8
        for (int j = 1; j <= H_HALF; ++j) {
            const int h = H_HALF - j;
            acc = fmaf(cj, fr[(n * H_HALF + h) * F_DIM + f], acc);
            acc = fmaf(-sj, fi[(n * H_HALF + h) * F_DIM + f], acc);
            const float cn = fmaf(cj, cb, -sj * sb);
            const float sn = fmaf(sj, cb, cj * sb);
            cj = cn; sj = sn;
        }
        const float y = fmaxf(fmaf(2.f, acc, 1.f), 0.f);
        const float wgt = (tid == 0 || tid == 99) ? 0.005f : 0.01f;  // trapz
        contrib = wgt * y;
    }
    #pragma unroll
    for (int off = 32; off > 0; off >>= 1)
        contrib += __shfl_xor(contrib, off, 64);
    __shared__ float red[2];
    if ((tid & 63) == 0) red[tid >> 6] = contrib;
    __syncthreads();
    if (tid == 0) c_out[n * F_DIM + f] = 1.f / (red[0] + red[1]);
}

// ---------------------------------------------------------------------------
// main (MFMA): per n, acc[16m x 16f] = sum_{k=0..511} A[m,k]*B[k,f] where
//   k even: A=cos(2pi*(k/2+1)*x_m),  B=fr[n, 255-k/2, f]
//   k odd:  A=sin(2pi*(k/2+1)*x_m),  B=-fi[n, 255-k/2, f]
// B staged once per block as f16 in LDS, rows (n,f) padded to 260 dwords.
// A generated in-register: fract + v_sin/v_cos (revolutions). 16 MFMA / n.
// Block = 512 threads = 8 waves; wave owns one 16-m tile. No K-loop barriers.
// Epilogue: proj=relu(1+2acc)*c, product over n in C-layout regs, lam-dot via
// quad shuffle reduce, float4 store by lanes 0/16/32/48.
// ---------------------------------------------------------------------------
__global__ __launch_bounds__(512, 4) void main_kernel(const float* __restrict__ x,
                                                      const float* __restrict__ fr,
                                                      const float* __restrict__ fi,
                                                      const float* __restrict__ lam,
                                                      const float* __restrict__ c_cond,
                                                      float* __restrict__ out) {
    __shared__ __align__(16) unsigned int Bls[48 * 260];   // 49920 B
    const int tid = threadIdx.x;

    // ---- prep: f32 factors -> packed f16 (cos-coef, sin-coef) dwords in LDS
    #pragma unroll
    for (int r = 0; r < 24; ++r) {
        const int idx = r * 512 + tid;        // = (n*256 + h)*16 + f
        const int f = idx & 15;
        const int h = (idx >> 4) & 255;
        const int n = idx >> 12;
        const float a = fr[idx];
        const float b = -fi[idx];
        Bls[(n * 16 + f) * 260 + (255 - h)] = pk(a, b);  // lo=fr, hi=-fi
    }
    __syncthreads();

    const int wave = tid >> 6;
    const int lane = tid & 63;
    const int l15 = lane & 15;     // A-row m; also B-col f; also D-col f
    const int q = lane >> 4;       // quad
    const int mbase = (blockIdx.x * 8 + wave) * 16;

    const float xv0 = x[(mbase + l15) * 3 + 0];
    const float xv1 = x[(mbase + l15) * 3 + 1];
    const float xv2 = x[(mbase + l15) * 3 + 2];

    float4_t accs[3];
    #pragma unroll
    for (int n = 0; n < 3; ++n) {
        const float xq = (n == 0) ? xv0 : (n == 1 ? xv1 : xv2);
        const float x2 = xq + xq;
        const float x3 = x2 + xq;
        const unsigned int* Brow = &Bls[(n * 16 + l15) * 260 + q * 4];
        float4_t acc = {0.f, 0.f, 0.f, 0.f};
        float jb = (float)(q * 4 + 1);         // j0 at step 0 for this quad
        #pragma unroll 4
        for (int s = 0; s < 16; ++s) {
            const int4 bv = *reinterpret_cast<const int4*>(Brow + s * 16);
            const half8_t bfrag = __builtin_bit_cast(half8_t, bv);
            const float v = jb * xq;
            const float u0 = FRACT1(v);
            const float u1 = FRACT1(v + xq);
            const float u2 = FRACT1(v + x2);
            const float u3 = FRACT1(v + x3);
            const int4 av = { (int)pk(COS2PI(u0), SIN2PI(u0)),
                              (int)pk(COS2PI(u1), SIN2PI(u1)),
                              (int)pk(COS2PI(u2), SIN2PI(u2)),
                              (int)pk(COS2PI(u3), SIN2PI(u3)) };
            const half8_t afrag = __builtin_bit_cast(half8_t, av);
            acc = __builtin_amdgcn_mfma_f32_16x16x32_f16(afrag, bfrag, acc, 0, 0, 0);
            jb += 16.f;
        }
        accs[n] = acc;
    }

    // ---- epilogue
    const float lamv = lam[l15];
    float r0 = 1.f, r1 = 1.f, r2 = 1.f, r3 = 1.f;
    #pragma unroll
    for (int n = 0; n < 3; ++n) {
        const float cc = c_cond[n * 16 + l15];
        r0 *= fmaxf(fmaf(2.f, accs[n][0], 1.f), 0.f) * cc;
        r1 *= fmaxf(fmaf(2.f, accs[n][1], 1.f), 0.f) * cc;
        r2 *= fmaxf(fmaf(2.f, accs[n][2], 1.f), 0.f) * cc;
        r3 *= fmaxf(fmaf(2.f, accs[n][3], 1.f), 0.f) * cc;
    }
    r0 *= lamv; r1 *= lamv; r2 *= lamv; r3 *= lamv;
    #pragma unroll
    for (int off = 1; off < 16; off <<= 1) {
        r0 += __shfl_xor(r0, off, 64);
        r1 += __shfl_xor(r1, off, 64);
        r2 += __shfl_xor(r2, off, 64);
        r3 += __shfl_xor(r3, off, 64);
    }
    if (l15 == 0) {   // lanes 0,16,32,48 hold rows m = q*4 + {0..3}
        float4 o = { r0, r1, r2, r3 };
        *reinterpret_cast<float4*>(out + mbase + q * 4) = o;
    }
}

extern "C" void kernel_launch(void* const* d_in, const int* in_sizes, int n_in,
                              void* d_out, int out_size, void* d_ws, size_t ws_size,
                              hipStream_t stream) {
    const float* x   = (const float*)d_in[0];   // (M, 3)
    const float* fr  = (const float*)d_in[1];   // (3, 256, 16)
    const float* fi  = (const float*)d_in[2];   // (3, 256, 16)
    const float* lam = (const float*)d_in[3];   // (16,)
    float* out = (float*)d_out;                 // (M,)
    float* c_ws = (float*)d_ws;                 // 48 floats: c[n,f]

    const int M = in_sizes[0] / NDIMS;

    cond_kernel<<<NDIMS * F_DIM, 128, 0, stream>>>(fr, fi, c_ws);
    main_kernel<<<M / 128, 512, 0, stream>>>(x, fr, fi, lam, c_ws, out);
}

// Round 6
// 86.373 us; speedup vs baseline: 1.4455x; 1.4455x over previous
//
#include <hip/hip_runtime.h>

#define NDIMS 3
#define H_HALF 256
#define F_DIM 16
#define PI_F 3.14159265358979323846f

typedef _Float16 half8_t __attribute__((ext_vector_type(8)));
typedef __fp16 pk2_t __attribute__((ext_vector_type(2)));   // return type of cvt_pkrtz
typedef float float4_t __attribute__((ext_vector_type(4)));

#if __has_builtin(__builtin_amdgcn_fractf)
#define FRACT1(u) __builtin_amdgcn_fractf(u)
#else
#define FRACT1(u) ((u) - floorf(u))
#endif
// v_sin_f32/v_cos_f32 take REVOLUTIONS (sin(2*pi*u)); input pre-reduced to [0,1).
#if __has_builtin(__builtin_amdgcn_sinf)
#define SIN2PI(u) __builtin_amdgcn_sinf(u)
#define COS2PI(u) __builtin_amdgcn_cosf(u)
#else
#define SIN2PI(u) __sinf(6.283185307f * (u))
#define COS2PI(u) __cosf(6.283185307f * (u))
#endif

// pack two f32 into an f16x2 dword (v_cvt_pkrtz_f16_f32)
static __device__ __forceinline__ unsigned int pk(float lo, float hi) {
    const pk2_t p = __builtin_amdgcn_cvt_pkrtz(lo, hi);
    return __builtin_bit_cast(unsigned int, p);
}

// ---------------------------------------------------------------------------
// cond_partial: partial trapz integrals. Grid = 3n x 7 t-chunks, 256 threads.
// thread = (tq = tid>>4 -> t-sample, f = tid&15): factor loads are per-lane
// COALESCED vector loads (16 dwords/wave, broadcast over t-lanes) -> load
// pipeline hides latency (vs s_load serialization: 60 us in R5).
// part_out[(n*7+chunk)*16+f] = sum over chunk's t of w(t)*relu(y(t,f))
// main's epilogue sums the 7 partials and takes 1/sum (no finalize kernel).
// ---------------------------------------------------------------------------
__global__ __launch_bounds__(256) void cond_partial_kernel(const float* __restrict__ fr,
                                                           const float* __restrict__ fi,
                                                           float* __restrict__ part_out) {
    const int n = blockIdx.x / 7;
    const int chunk = blockIdx.x % 7;
    const int tid = threadIdx.x;
    const int f = tid & 15;
    const int tq = tid >> 4;            // 0..15 within block
    const int t_idx = chunk * 16 + tq;  // 0..111 (valid < 100)
    const float t = 0.01f + 0.01f * (float)t_idx;
    const float beta = 2.f * PI_F * t;
    const float cb = __cosf(beta), sb = __sinf(beta);
    float cj = cb, sj = sb;             // cos/sin(2pi*1*t)
    const float* frn = fr + n * H_HALF * F_DIM + f;
    const float* fin = fi + n * H_HALF * F_DIM + f;
    float acc = 0.f;
    #pragma unroll 8
    for (int j = 1; j <= H_HALF; ++j) {
        const int h = H_HALF - j;
        acc = fmaf(cj, frn[h * F_DIM], acc);
        acc = fmaf(-sj, fin[h * F_DIM], acc);
        const float cn = fmaf(cj, cb, -sj * sb);   // advance angle by beta
        const float sn = fmaf(sj, cb, cj * sb);
        cj = cn; sj = sn;
    }
    const float y = fmaxf(fmaf(2.f, acc, 1.f), 0.f);
    const float wgt = (t_idx == 0 || t_idx == 99) ? 0.005f : 0.01f;  // trapz weights
    float contrib = (t_idx < 100) ? wgt * y : 0.f;
    // reduce over tq within wave (lanes differing in bits 4,5)
    contrib += __shfl_xor(contrib, 16, 64);
    contrib += __shfl_xor(contrib, 32, 64);
    __shared__ float red[4][16];
    const int wv = tid >> 6;
    const int lane = tid & 63;
    if (lane < 16) red[wv][lane] = contrib;  // lanes 0..15 hold f = lane
    __syncthreads();
    if (tid < 16) {
        part_out[blockIdx.x * 16 + tid] =
            (red[0][tid] + red[1][tid]) + (red[2][tid] + red[3][tid]);
    }
}

// ---------------------------------------------------------------------------
// main (MFMA): per n, acc[16m x 16f] = sum_{k=0..511} A[m,k]*B[k,f] where
//   k even: A=cos(2pi*(k/2+1)*x_m),  B=fr[n, 255-k/2, f]
//   k odd:  A=sin(2pi*(k/2+1)*x_m),  B=-fi[n, 255-k/2, f]
// B staged once per block as f16 in LDS, rows (n,f) padded to 260 dwords.
// A generated in-register: fract + v_sin/v_cos (revolutions). 16 MFMA / n.
// Block = 512 threads = 8 waves; wave owns one 16-m tile. No K-loop barriers.
// Epilogue: c = 1/sum(partials); proj=relu(1+2acc)*c; product over n in
// C-layout regs; lam-dot via quad shuffle reduce; float4 store.
// ---------------------------------------------------------------------------
__global__ __launch_bounds__(512, 4) void main_kernel(const float* __restrict__ x,
                                                      const float* __restrict__ fr,
                                                      const float* __restrict__ fi,
                                                      const float* __restrict__ lam,
                                                      const float* __restrict__ part,
                                                      float* __restrict__ out) {
    __shared__ __align__(16) unsigned int Bls[48 * 260];   // 49920 B
    const int tid = threadIdx.x;

    // ---- prep: f32 factors -> packed f16 (cos-coef, sin-coef) dwords in LDS
    #pragma unroll
    for (int r = 0; r < 24; ++r) {
        const int idx = r * 512 + tid;        // = (n*256 + h)*16 + f
        const int f = idx & 15;
        const int h = (idx >> 4) & 255;
        const int n = idx >> 12;
        const float a = fr[idx];
        const float b = -fi[idx];
        Bls[(n * 16 + f) * 260 + (255 - h)] = pk(a, b);  // lo=fr, hi=-fi
    }
    __syncthreads();

    const int wave = tid >> 6;
    const int lane = tid & 63;
    const int l15 = lane & 15;     // A-row m; also B-col f; also D-col f
    const int q = lane >> 4;       // quad
    const int mbase = (blockIdx.x * 8 + wave) * 16;

    const float xv0 = x[(mbase + l15) * 3 + 0];
    const float xv1 = x[(mbase + l15) * 3 + 1];
    const float xv2 = x[(mbase + l15) * 3 + 2];

    float4_t accs[3];
    #pragma unroll
    for (int n = 0; n < 3; ++n) {
        const float xq = (n == 0) ? xv0 : (n == 1 ? xv1 : xv2);
        const float x2 = xq + xq;
        const float x3 = x2 + xq;
        const unsigned int* Brow = &Bls[(n * 16 + l15) * 260 + q * 4];
        float4_t acc = {0.f, 0.f, 0.f, 0.f};
        float jb = (float)(q * 4 + 1);         // j0 at step 0 for this quad
        #pragma unroll 4
        for (int s = 0; s < 16; ++s) {
            const int4 bv = *reinterpret_cast<const int4*>(Brow + s * 16);
            const half8_t bfrag = __builtin_bit_cast(half8_t, bv);
            const float v = jb * xq;
            const float u0 = FRACT1(v);
            const float u1 = FRACT1(v + xq);
            const float u2 = FRACT1(v + x2);
            const float u3 = FRACT1(v + x3);
            const int4 av = { (int)pk(COS2PI(u0), SIN2PI(u0)),
                              (int)pk(COS2PI(u1), SIN2PI(u1)),
                              (int)pk(COS2PI(u2), SIN2PI(u2)),
                              (int)pk(COS2PI(u3), SIN2PI(u3)) };
            const half8_t afrag = __builtin_bit_cast(half8_t, av);
            acc = __builtin_amdgcn_mfma_f32_16x16x32_f16(afrag, bfrag, acc, 0, 0, 0);
            jb += 16.f;
        }
        accs[n] = acc;
    }

    // ---- epilogue: conditionals from partials, product over n, lam-dot
    const float lamv = lam[l15];
    float r0 = 1.f, r1 = 1.f, r2 = 1.f, r3 = 1.f;
    #pragma unroll
    for (int n = 0; n < 3; ++n) {
        float s = 0.f;
        #pragma unroll
        for (int c7 = 0; c7 < 7; ++c7) s += part[(n * 7 + c7) * 16 + l15];
        const float cc = 1.f / s;
        r0 *= fmaxf(fmaf(2.f, accs[n][0], 1.f), 0.f) * cc;
        r1 *= fmaxf(fmaf(2.f, accs[n][1], 1.f), 0.f) * cc;
        r2 *= fmaxf(fmaf(2.f, accs[n][2], 1.f), 0.f) * cc;
        r3 *= fmaxf(fmaf(2.f, accs[n][3], 1.f), 0.f) * cc;
    }
    r0 *= lamv; r1 *= lamv; r2 *= lamv; r3 *= lamv;
    #pragma unroll
    for (int off = 1; off < 16; off <<= 1) {
        r0 += __shfl_xor(r0, off, 64);
        r1 += __shfl_xor(r1, off, 64);
        r2 += __shfl_xor(r2, off, 64);
        r3 += __shfl_xor(r3, off, 64);
    }
    if (l15 == 0) {   // lanes 0,16,32,48 hold rows m = q*4 + {0..3}
        float4 o = { r0, r1, r2, r3 };
        *reinterpret_cast<float4*>(out + mbase + q * 4) = o;
    }
}

extern "C" void kernel_launch(void* const* d_in, const int* in_sizes, int n_in,
                              void* d_out, int out_size, void* d_ws, size_t ws_size,
                              hipStream_t stream) {
    const float* x   = (const float*)d_in[0];   // (M, 3)
    const float* fr  = (const float*)d_in[1];   // (3, 256, 16)
    const float* fi  = (const float*)d_in[2];   // (3, 256, 16)
    const float* lam = (const float*)d_in[3];   // (16,)
    float* out = (float*)d_out;                 // (M,)
    float* part = (float*)d_ws;                 // 3*7*16 = 336 floats (trapz partials)

    const int M = in_sizes[0] / NDIMS;

    cond_partial_kernel<<<NDIMS * 7, 256, 0, stream>>>(fr, fi, part);
    main_kernel<<<M / 128, 512, 0, stream>>>(x, fr, fi, lam, part, out);
}

// Round 7
// 80.596 us; speedup vs baseline: 1.5492x; 1.0717x over previous
//
#include <hip/hip_runtime.h>

#define NDIMS 3
#define H_HALF 256
#define F_DIM 16
#define PI_F 3.14159265358979323846f

typedef _Float16 half8_t __attribute__((ext_vector_type(8)));
typedef __fp16 pk2_t __attribute__((ext_vector_type(2)));   // return type of cvt_pkrtz
typedef float float4_t __attribute__((ext_vector_type(4)));

#if __has_builtin(__builtin_amdgcn_fractf)
#define FRACT1(u) __builtin_amdgcn_fractf(u)
#else
#define FRACT1(u) ((u) - floorf(u))
#endif
// v_sin_f32/v_cos_f32 take REVOLUTIONS (sin(2*pi*u)); input pre-reduced to [0,1).
#if __has_builtin(__builtin_amdgcn_sinf)
#define SIN2PI(u) __builtin_amdgcn_sinf(u)
#define COS2PI(u) __builtin_amdgcn_cosf(u)
#else
#define SIN2PI(u) __sinf(6.283185307f * (u))
#define COS2PI(u) __cosf(6.283185307f * (u))
#endif

// pack two f32 into an f16x2 dword (v_cvt_pkrtz_f16_f32)
static __device__ __forceinline__ unsigned int pk(float lo, float hi) {
    const pk2_t p = __builtin_amdgcn_cvt_pkrtz(lo, hi);
    return __builtin_bit_cast(unsigned int, p);
}

// ---------------------------------------------------------------------------
// cond_partial: partial trapz integrals. Grid = 3n x 7 t-chunks, 256 threads.
// thread = (tq, f): factor loads per-lane coalesced, pipeline hides latency.
// main's epilogue sums the 7 partials and takes 1/sum (no finalize kernel).
// ---------------------------------------------------------------------------
__global__ __launch_bounds__(256) void cond_partial_kernel(const float* __restrict__ fr,
                                                           const float* __restrict__ fi,
                                                           float* __restrict__ part_out) {
    const int n = blockIdx.x / 7;
    const int chunk = blockIdx.x % 7;
    const int tid = threadIdx.x;
    const int f = tid & 15;
    const int tq = tid >> 4;            // 0..15 within block
    const int t_idx = chunk * 16 + tq;  // 0..111 (valid < 100)
    const float t = 0.01f + 0.01f * (float)t_idx;
    const float beta = 2.f * PI_F * t;
    const float cb = __cosf(beta), sb = __sinf(beta);
    float cj = cb, sj = sb;             // cos/sin(2pi*1*t)
    const float* frn = fr + n * H_HALF * F_DIM + f;
    const float* fin = fi + n * H_HALF * F_DIM + f;
    float acc = 0.f;
    #pragma unroll 8
    for (int j = 1; j <= H_HALF; ++j) {
        const int h = H_HALF - j;
        acc = fmaf(cj, frn[h * F_DIM], acc);
        acc = fmaf(-sj, fin[h * F_DIM], acc);
        const float cn = fmaf(cj, cb, -sj * sb);   // advance angle by beta
        const float sn = fmaf(sj, cb, cj * sb);
        cj = cn; sj = sn;
    }
    const float y = fmaxf(fmaf(2.f, acc, 1.f), 0.f);
    const float wgt = (t_idx == 0 || t_idx == 99) ? 0.005f : 0.01f;  // trapz weights
    float contrib = (t_idx < 100) ? wgt * y : 0.f;
    contrib += __shfl_xor(contrib, 16, 64);
    contrib += __shfl_xor(contrib, 32, 64);
    __shared__ float red[4][16];
    const int wv = tid >> 6;
    const int lane = tid & 63;
    if (lane < 16) red[wv][lane] = contrib;  // lanes 0..15 hold f = lane
    __syncthreads();
    if (tid < 16) {
        part_out[blockIdx.x * 16 + tid] =
            (red[0][tid] + red[1][tid]) + (red[2][tid] + red[3][tid]);
    }
}

// ---------------------------------------------------------------------------
// main (MFMA): per n, acc[16m x 16f] = sum_{k=0..511} A[m,k]*B[k,f] where
//   k even: A=cos(2pi*(k/2+1)*x_m),  B=fr[n, 255-k/2, f]
//   k odd:  A=sin(2pi*(k/2+1)*x_m),  B=-fi[n, 255-k/2, f]
// B staged once per block as f16 in LDS ((n,f)-rows padded to 260 dwords).
// A fragments: 4 (cos,sin) pairs per lane, advanced per step by the CONSTANT
// rotation D = 2pi*16*x via 4 FMAs/pair (transcendentals only at init: 10/n
// instead of 128/n — R6's per-step v_sin/v_cos was the VALU hot spot).
// Block = 512 threads = 8 waves; wave owns one 16-m tile. No K-loop barriers.
// ---------------------------------------------------------------------------
__global__ __launch_bounds__(512, 4) void main_kernel(const float* __restrict__ x,
                                                      const float* __restrict__ fr,
                                                      const float* __restrict__ fi,
                                                      const float* __restrict__ lam,
                                                      const float* __restrict__ part,
                                                      float* __restrict__ out) {
    __shared__ __align__(16) unsigned int Bls[48 * 260];   // 49920 B
    const int tid = threadIdx.x;

    // ---- prep: f32 factors -> packed f16 (cos-coef, sin-coef) dwords in LDS
    #pragma unroll
    for (int r = 0; r < 24; ++r) {
        const int idx = r * 512 + tid;        // = (n*256 + h)*16 + f
        const int f = idx & 15;
        const int h = (idx >> 4) & 255;
        const int n = idx >> 12;
        Bls[(n * 16 + f) * 260 + (255 - h)] = pk(fr[idx], -fi[idx]);  // lo=fr, hi=-fi
    }
    __syncthreads();

    const int wave = tid >> 6;
    const int lane = tid & 63;
    const int l15 = lane & 15;     // A-row m; also B-col f; also D-col f
    const int q = lane >> 4;       // quad
    const int mbase = (blockIdx.x * 8 + wave) * 16;

    const float xv0 = x[(mbase + l15) * 3 + 0];
    const float xv1 = x[(mbase + l15) * 3 + 1];
    const float xv2 = x[(mbase + l15) * 3 + 2];

    float4_t accs[3];
    #pragma unroll
    for (int n = 0; n < 3; ++n) {
        const float xq = (n == 0) ? xv0 : (n == 1 ? xv1 : xv2);
        // init 4 pairs at j = q*4 + 1 + i, and the step rotation D = 16*x
        const float j0 = (float)(q * 4 + 1);
        const float u0 = FRACT1(j0 * xq);
        const float u1 = FRACT1((j0 + 1.f) * xq);
        const float u2 = FRACT1((j0 + 2.f) * xq);
        const float u3 = FRACT1((j0 + 3.f) * xq);
        float c0 = COS2PI(u0), s0 = SIN2PI(u0);
        float c1 = COS2PI(u1), s1 = SIN2PI(u1);
        float c2 = COS2PI(u2), s2 = SIN2PI(u2);
        float c3 = COS2PI(u3), s3 = SIN2PI(u3);
        const float ud = FRACT1(16.f * xq);
        const float cD = COS2PI(ud), sD = SIN2PI(ud);

        const unsigned int* Brow = &Bls[(n * 16 + l15) * 260 + q * 4];
        float4_t acc = {0.f, 0.f, 0.f, 0.f};
        #pragma unroll
        for (int s = 0; s < 16; ++s) {
            const int4 bv = *reinterpret_cast<const int4*>(Brow + s * 16);
            const half8_t bfrag = __builtin_bit_cast(half8_t, bv);
            const int4 av = { (int)pk(c0, s0), (int)pk(c1, s1),
                              (int)pk(c2, s2), (int)pk(c3, s3) };
            const half8_t afrag = __builtin_bit_cast(half8_t, av);
            acc = __builtin_amdgcn_mfma_f32_16x16x32_f16(afrag, bfrag, acc, 0, 0, 0);
            // advance all pairs by D (unit rotation, 4 FMAs each)
            float t0 = fmaf(c0, cD, -s0 * sD); s0 = fmaf(s0, cD, c0 * sD); c0 = t0;
            float t1 = fmaf(c1, cD, -s1 * sD); s1 = fmaf(s1, cD, c1 * sD); c1 = t1;
            float t2 = fmaf(c2, cD, -s2 * sD); s2 = fmaf(s2, cD, c2 * sD); c2 = t2;
            float t3 = fmaf(c3, cD, -s3 * sD); s3 = fmaf(s3, cD, c3 * sD); c3 = t3;
        }
        accs[n] = acc;
    }

    // ---- epilogue: conditionals from partials, product over n, lam-dot
    const float lamv = lam[l15];
    float r0 = 1.f, r1 = 1.f, r2 = 1.f, r3 = 1.f;
    #pragma unroll
    for (int n = 0; n < 3; ++n) {
        float s = 0.f;
        #pragma unroll
        for (int c7 = 0; c7 < 7; ++c7) s += part[(n * 7 + c7) * 16 + l15];
        const float cc = 1.f / s;
        r0 *= fmaxf(fmaf(2.f, accs[n][0], 1.f), 0.f) * cc;
        r1 *= fmaxf(fmaf(2.f, accs[n][1], 1.f), 0.f) * cc;
        r2 *= fmaxf(fmaf(2.f, accs[n][2], 1.f), 0.f) * cc;
        r3 *= fmaxf(fmaf(2.f, accs[n][3], 1.f), 0.f) * cc;
    }
    r0 *= lamv; r1 *= lamv; r2 *= lamv; r3 *= lamv;
    #pragma unroll
    for (int off = 1; off < 16; off <<= 1) {
        r0 += __shfl_xor(r0, off, 64);
        r1 += __shfl_xor(r1, off, 64);
        r2 += __shfl_xor(r2, off, 64);
        r3 += __shfl_xor(r3, off, 64);
    }
    if (l15 == 0) {   // lanes 0,16,32,48 hold rows m = q*4 + {0..3}
        float4 o = { r0, r1, r2, r3 };
        *reinterpret_cast<float4*>(out + mbase + q * 4) = o;
    }
}

extern "C" void kernel_launch(void* const* d_in, const int* in_sizes, int n_in,
                              void* d_out, int out_size, void* d_ws, size_t ws_size,
                              hipStream_t stream) {
    const float* x   = (const float*)d_in[0];   // (M, 3)
    const float* fr  = (const float*)d_in[1];   // (3, 256, 16)
    const float* fi  = (const float*)d_in[2];   // (3, 256, 16)
    const float* lam = (const float*)d_in[3];   // (16,)
    float* out = (float*)d_out;                 // (M,)
    float* part = (float*)d_ws;                 // 3*7*16 = 336 floats (trapz partials)

    const int M = in_sizes[0] / NDIMS;

    cond_partial_kernel<<<NDIMS * 7, 256, 0, stream>>>(fr, fi, part);
    main_kernel<<<M / 128, 512, 0, stream>>>(x, fr, fi, lam, part, out);
}

// Round 8
// 80.048 us; speedup vs baseline: 1.5598x; 1.0068x over previous
//
#include <hip/hip_runtime.h>

#define NDIMS 3
#define H_HALF 256
#define F_DIM 16
#define PI_F 3.14159265358979323846f

typedef _Float16 half8_t __attribute__((ext_vector_type(8)));
typedef _Float16 h2 __attribute__((ext_vector_type(2)));
typedef __fp16 pk2_t __attribute__((ext_vector_type(2)));   // return type of cvt_pkrtz
typedef float float4_t __attribute__((ext_vector_type(4)));

#if __has_builtin(__builtin_amdgcn_fractf)
#define FRACT1(u) __builtin_amdgcn_fractf(u)
#else
#define FRACT1(u) ((u) - floorf(u))
#endif
// v_sin_f32/v_cos_f32 take REVOLUTIONS (sin(2*pi*u)); input pre-reduced to [0,1).
#if __has_builtin(__builtin_amdgcn_sinf)
#define SIN2PI(u) __builtin_amdgcn_sinf(u)
#define COS2PI(u) __builtin_amdgcn_cosf(u)
#else
#define SIN2PI(u) __sinf(6.283185307f * (u))
#define COS2PI(u) __cosf(6.283185307f * (u))
#endif

// pack two f32 into an f16x2 dword (v_cvt_pkrtz_f16_f32)
static __device__ __forceinline__ unsigned int pk(float lo, float hi) {
    const pk2_t p = __builtin_amdgcn_cvt_pkrtz(lo, hi);
    return __builtin_bit_cast(unsigned int, p);
}
static __device__ __forceinline__ h2 pkh(float lo, float hi) {
    const pk2_t p = __builtin_amdgcn_cvt_pkrtz(lo, hi);
    return __builtin_bit_cast(h2, p);
}

// ---------------------------------------------------------------------------
// cond_partial: partial trapz integrals. Grid = 3n x 7 t-chunks, 256 threads.
// thread = (tq, f): factor loads per-lane coalesced, pipeline hides latency.
// main's epilogue sums the 7 partials and takes 1/sum (no finalize kernel).
// ---------------------------------------------------------------------------
__global__ __launch_bounds__(256) void cond_partial_kernel(const float* __restrict__ fr,
                                                           const float* __restrict__ fi,
                                                           float* __restrict__ part_out) {
    const int n = blockIdx.x / 7;
    const int chunk = blockIdx.x % 7;
    const int tid = threadIdx.x;
    const int f = tid & 15;
    const int tq = tid >> 4;            // 0..15 within block
    const int t_idx = chunk * 16 + tq;  // 0..111 (valid < 100)
    const float t = 0.01f + 0.01f * (float)t_idx;
    const float beta = 2.f * PI_F * t;
    const float cb = __cosf(beta), sb = __sinf(beta);
    float cj = cb, sj = sb;             // cos/sin(2pi*1*t)
    const float* frn = fr + n * H_HALF * F_DIM + f;
    const float* fin = fi + n * H_HALF * F_DIM + f;
    float acc = 0.f;
    #pragma unroll 8
    for (int j = 1; j <= H_HALF; ++j) {
        const int h = H_HALF - j;
        acc = fmaf(cj, frn[h * F_DIM], acc);
        acc = fmaf(-sj, fin[h * F_DIM], acc);
        const float cn = fmaf(cj, cb, -sj * sb);   // advance angle by beta
        const float sn = fmaf(sj, cb, cj * sb);
        cj = cn; sj = sn;
    }
    const float y = fmaxf(fmaf(2.f, acc, 1.f), 0.f);
    const float wgt = (t_idx == 0 || t_idx == 99) ? 0.005f : 0.01f;  // trapz weights
    float contrib = (t_idx < 100) ? wgt * y : 0.f;
    contrib += __shfl_xor(contrib, 16, 64);
    contrib += __shfl_xor(contrib, 32, 64);
    __shared__ float red[4][16];
    const int wv = tid >> 6;
    const int lane = tid & 63;
    if (lane < 16) red[wv][lane] = contrib;  // lanes 0..15 hold f = lane
    __syncthreads();
    if (tid < 16) {
        part_out[blockIdx.x * 16 + tid] =
            (red[0][tid] + red[1][tid]) + (red[2][tid] + red[3][tid]);
    }
}

// ---------------------------------------------------------------------------
// main (MFMA): per n, acc[16m x 16f] = sum_{k=0..511} A[m,k]*B[k,f] where
//   k even: A=cos(2pi*(k/2+1)*x_m),  B=fr[n, 255-k/2, f]
//   k odd:  A=sin(2pi*(k/2+1)*x_m),  B=-fi[n, 255-k/2, f]
// B staged once per block as f16 in LDS ((n,f)-rows padded to 260 dwords).
// A fragments: ONE f32 (cos,sin) base pair per lane (j = q*4+1), advanced per
// step by the constant rotation D = 2pi*16*x (4 f32 ops); the 3 sibling pairs
// (j+1..j+3) derived ONE-SHOT per step in packed f16 (2 v_pk ops each) from
// f16-packed per-n constants (cos/sin of 2pi*d*x, d=1..3). 12 VALU/step vs 20.
// No error accumulation in derived pairs (base chain stays f32).
// Block = 512 threads = 8 waves; wave owns one 16-m tile. No K-loop barriers.
// ---------------------------------------------------------------------------
__global__ __launch_bounds__(512, 4) void main_kernel(const float* __restrict__ x,
                                                      const float* __restrict__ fr,
                                                      const float* __restrict__ fi,
                                                      const float* __restrict__ lam,
                                                      const float* __restrict__ part,
                                                      float* __restrict__ out) {
    __shared__ __align__(16) unsigned int Bls[48 * 260];   // 49920 B
    const int tid = threadIdx.x;

    // ---- prep: f32 factors -> packed f16 (cos-coef, sin-coef) dwords in LDS
    // float4 loads: 12288 floats = 3072 float4; 6 iters x 512 threads.
    {
        const float4* fr4 = (const float4*)fr;
        const float4* fi4 = (const float4*)fi;
        #pragma unroll
        for (int r = 0; r < 6; ++r) {
            const int i4 = r * 512 + tid;
            const float4 a = fr4[i4];
            const float4 b = fi4[i4];
            const int n = i4 >> 10;
            const int h = (i4 >> 2) & 255;
            const int f0 = (i4 & 3) * 4;
            const int base = (n * 16 + f0) * 260 + (255 - h);
            Bls[base      ] = pk(a.x, -b.x);
            Bls[base + 260] = pk(a.y, -b.y);
            Bls[base + 520] = pk(a.z, -b.z);
            Bls[base + 780] = pk(a.w, -b.w);
        }
    }
    __syncthreads();

    const int wave = tid >> 6;
    const int lane = tid & 63;
    const int l15 = lane & 15;     // A-row m; also B-col f; also D-col f
    const int q = lane >> 4;       // quad
    const int mbase = (blockIdx.x * 8 + wave) * 16;

    const float xv0 = x[(mbase + l15) * 3 + 0];
    const float xv1 = x[(mbase + l15) * 3 + 1];
    const float xv2 = x[(mbase + l15) * 3 + 2];
    // hoist epilogue loads (latency hidden behind K-loops)
    float psum[3];
    #pragma unroll
    for (int n = 0; n < 3; ++n) {
        float s = 0.f;
        #pragma unroll
        for (int c7 = 0; c7 < 7; ++c7) s += part[(n * 7 + c7) * 16 + l15];
        psum[n] = s;
    }
    const float lamv = lam[l15];

    float4_t accs[3];
    #pragma unroll
    for (int n = 0; n < 3; ++n) {
        const float xq = (n == 0) ? xv0 : (n == 1 ? xv1 : xv2);
        // sibling-offset rotations d = 1..3 (f32-accurate, then f16-packed)
        const float u1 = FRACT1(xq);
        const float cd1 = COS2PI(u1), sd1 = SIN2PI(u1);
        const float cd2 = fmaf(cd1, cd1, -sd1 * sd1), sd2 = 2.f * sd1 * cd1;
        const float cd3 = fmaf(cd2, cd1, -sd2 * sd1), sd3 = fmaf(sd2, cd1, cd2 * sd1);
        const h2 cc1 = pkh(cd1, cd1), ns1 = pkh(-sd1, sd1);
        const h2 cc2 = pkh(cd2, cd2), ns2 = pkh(-sd2, sd2);
        const h2 cc3 = pkh(cd3, cd3), ns3 = pkh(-sd3, sd3);
        // step rotation D = 16x, base pair at j0 = q*4+1
        const float ud = FRACT1(16.f * xq);
        const float cD = COS2PI(ud), sD = SIN2PI(ud);
        const float v0 = FRACT1((float)(q * 4 + 1) * xq);
        float c0 = COS2PI(v0), s0 = SIN2PI(v0);

        const unsigned int* Brow = &Bls[(n * 16 + l15) * 260 + q * 4];
        float4_t acc = {0.f, 0.f, 0.f, 0.f};
        #pragma unroll
        for (int s = 0; s < 16; ++s) {
            const int4 bv = *reinterpret_cast<const int4*>(Brow + s * 16);
            const half8_t bfrag = __builtin_bit_cast(half8_t, bv);
            const h2 b0 = pkh(c0, s0);          // (c,s) of base pair
            const h2 bsw = pkh(s0, c0);         // swapped
            const h2 d1 = __builtin_elementwise_fma(bsw, ns1, b0 * cc1);
            const h2 d2 = __builtin_elementwise_fma(bsw, ns2, b0 * cc2);
            const h2 d3 = __builtin_elementwise_fma(bsw, ns3, b0 * cc3);
            const int4 av = { __builtin_bit_cast(int, b0), __builtin_bit_cast(int, d1),
                              __builtin_bit_cast(int, d2), __builtin_bit_cast(int, d3) };
            const half8_t afrag = __builtin_bit_cast(half8_t, av);
            acc = __builtin_amdgcn_mfma_f32_16x16x32_f16(afrag, bfrag, acc, 0, 0, 0);
            // advance base by D (f32 — accuracy-carrying chain)
            const float t0 = fmaf(c0, cD, -s0 * sD);
            s0 = fmaf(s0, cD, c0 * sD);
            c0 = t0;
        }
        accs[n] = acc;
    }

    // ---- epilogue: conditionals from partials, product over n, lam-dot
    float r0 = 1.f, r1 = 1.f, r2 = 1.f, r3 = 1.f;
    #pragma unroll
    for (int n = 0; n < 3; ++n) {
        const float cc = 1.f / psum[n];
        r0 *= fmaxf(fmaf(2.f, accs[n][0], 1.f), 0.f) * cc;
        r1 *= fmaxf(fmaf(2.f, accs[n][1], 1.f), 0.f) * cc;
        r2 *= fmaxf(fmaf(2.f, accs[n][2], 1.f), 0.f) * cc;
        r3 *= fmaxf(fmaf(2.f, accs[n][3], 1.f), 0.f) * cc;
    }
    r0 *= lamv; r1 *= lamv; r2 *= lamv; r3 *= lamv;
    #pragma unroll
    for (int off = 1; off < 16; off <<= 1) {
        r0 += __shfl_xor(r0, off, 64);
        r1 += __shfl_xor(r1, off, 64);
        r2 += __shfl_xor(r2, off, 64);
        r3 += __shfl_xor(r3, off, 64);
    }
    if (l15 == 0) {   // lanes 0,16,32,48 hold rows m = q*4 + {0..3}
        float4 o = { r0, r1, r2, r3 };
        *reinterpret_cast<float4*>(out + mbase + q * 4) = o;
    }
}

extern "C" void kernel_launch(void* const* d_in, const int* in_sizes, int n_in,
                              void* d_out, int out_size, void* d_ws, size_t ws_size,
                              hipStream_t stream) {
    const float* x   = (const float*)d_in[0];   // (M, 3)
    const float* fr  = (const float*)d_in[1];   // (3, 256, 16)
    const float* fi  = (const float*)d_in[2];   // (3, 256, 16)
    const float* lam = (const float*)d_in[3];   // (16,)
    float* out = (float*)d_out;                 // (M,)
    float* part = (float*)d_ws;                 // 3*7*16 = 336 floats (trapz partials)

    const int M = in_sizes[0] / NDIMS;

    cond_partial_kernel<<<NDIMS * 7, 256, 0, stream>>>(fr, fi, part);
    main_kernel<<<M / 128, 512, 0, stream>>>(x, fr, fi, lam, part, out);
}